// Round 1
// baseline (785.927 us; speedup 1.0000x reference)
//
#include <hip/hip_runtime.h>
#include <math.h>

#define NSAMP 4194304
#define LAYERS 256
#define SPT 8   // samples per thread

// ws float layout:
// [0]=amp [1]=d [2]=f3000 (f32(freq)*3000) [3]=c [4]=b_out [5..8]=w_out[0..3]
// [16 .. 16+4096)      Wfold[L][4][4] = W * (freq*30)/(2pi)
// [16+4096 .. +1024)   Bfold[L][4]    = (freq*30*b + c)/(2pi)

__global__ void prep_kernel(
    const float* __restrict__ w_hidden, const float* __restrict__ b_hidden,
    const float* __restrict__ w_out,   const float* __restrict__ b_out,
    const float* __restrict__ a_param, const float* __restrict__ b_param,
    const float* __restrict__ c_param, const float* __restrict__ d_param,
    float* __restrict__ ws)
{
  const double TWO_PI = 6.283185307179586476925286766559;
  int idx = blockIdx.x * blockDim.x + threadIdx.x;
  // replicate reference rounding: freq = f32(exp(b)), g = f32(freq*30)
  float freqf = (float)exp((double)b_param[0]);
  float gf = (float)((double)freqf * 30.0);
  double scale = (double)gf / TWO_PI;
  if (idx < 4096) {
    ws[16 + idx] = (float)((double)w_hidden[idx] * scale);
  } else if (idx < 5120) {
    int bi = idx - 4096;
    ws[16 + 4096 + bi] =
        (float)(((double)gf * (double)b_hidden[bi] + (double)c_param[0]) / TWO_PI);
  } else if (idx == 5120) {
    ws[0] = (float)exp((double)a_param[0]);       // amp
    ws[1] = d_param[0];
    ws[2] = (float)((double)freqf * 3000.0);      // f3000
    ws[3] = c_param[0];
    ws[4] = b_out[0];
    ws[5] = w_out[0]; ws[6] = w_out[1]; ws[7] = w_out[2]; ws[8] = w_out[3];
  }
}

#if defined(__has_builtin)
#if __has_builtin(__builtin_amdgcn_sinf)
#define HAVE_SINF_BUILTIN 1
#endif
#endif

// hardware sin: input in revolutions, computes sin(2*pi*x)
__device__ __forceinline__ float vsin_rev(float x) {
#ifdef HAVE_SINF_BUILTIN
  return __builtin_amdgcn_sinf(x);
#else
  float r;
  asm("v_sin_f32 %0, %1" : "=v"(r) : "v"(x));
  return r;
#endif
}

// accurate sin for the first layer (radians, |A| up to ~3e4):
// double Cody-Waite reduction + degree-13 Taylor (error << f32 ulp)
__device__ __forceinline__ float sin_first(float A) {
  double x = (double)A;
  double kd = rint(x * 0.31830988618379067154);   // 1/pi
  double r  = fma(-kd, 3.1415926535897931159979634685, x);
  r = fma(-kd, 1.2246467991473531772e-16, r);     // pi tail
  double r2 = r * r;
  double p = 1.6059043836821613e-10;              // 1/13!
  p = fma(r2, p, -2.5052108385441718775e-8);      // -1/11!
  p = fma(r2, p,  2.7557319223985890653e-6);      //  1/9!
  p = fma(r2, p, -1.9841269841269841270e-4);      // -1/7!
  p = fma(r2, p,  8.3333333333333333333e-3);      //  1/5!
  p = fma(r2, p, -1.6666666666666666667e-1);      // -1/3!
  double s = fma(r2 * r, p, r);
  int ki = (int)kd;
  if (ki & 1) s = -s;
  return (float)s;
}

__global__ __launch_bounds__(256) void siren_main(
    const float* __restrict__ coords,
    const float* __restrict__ w_first, const float* __restrict__ b_first,
    const float* __restrict__ ws, float* __restrict__ out)
{
  const int tid = blockIdx.x * blockDim.x + threadIdx.x;   // 0 .. NSAMP/SPT-1
  const float amp = ws[0], dpar = ws[1], f3000 = ws[2], cpar = ws[3];

  float c[SPT];
  const float4* cp4 = reinterpret_cast<const float4*>(coords) + tid * (SPT / 4);
#pragma unroll
  for (int q = 0; q < SPT / 4; ++q) {
    float4 v = cp4[q];
    c[4*q+0] = v.x; c[4*q+1] = v.y; c[4*q+2] = v.z; c[4*q+3] = v.w;
  }

  float h[SPT][4];
#pragma unroll
  for (int s = 0; s < SPT; ++s) {
#pragma unroll
    for (int i = 0; i < 4; ++i) {
      // replicate reference fp32 op order exactly (no contraction):
      float t = __fmul_rn(c[s], w_first[i]);
      t = __fadd_rn(t, b_first[i]);
      float A = __fadd_rn(__fmul_rn(f3000, t), cpar);
      float sn = sin_first(A);
      h[s][i] = __fadd_rn(__fmul_rn(amp, sn), dpar);
    }
  }

  const float* __restrict__ Wp = ws + 16;
  const float* __restrict__ Bp = ws + 16 + 4096;

  for (int l = 0; l < LAYERS; ++l) {
    float w[16], b4[4];
#pragma unroll
    for (int k = 0; k < 16; ++k) w[k] = Wp[l * 16 + k];
#pragma unroll
    for (int k = 0; k < 4; ++k) b4[k] = Bp[l * 4 + k];
#pragma unroll
    for (int s = 0; s < SPT; ++s) {
      float z[4];
#pragma unroll
      for (int i = 0; i < 4; ++i) {
        float acc = b4[i];
#pragma unroll
        for (int j = 0; j < 4; ++j) acc = fmaf(w[i * 4 + j], h[s][j], acc);
        z[i] = acc;
      }
#pragma unroll
      for (int i = 0; i < 4; ++i) {
        float sn = vsin_rev(z[i]);                 // z is in revolutions (folded 1/2pi)
        h[s][i] = __fadd_rn(__fmul_rn(amp, sn), dpar);
      }
    }
  }

  const float wo0 = ws[5], wo1 = ws[6], wo2 = ws[7], wo3 = ws[8], bo = ws[4];
  float o[SPT];
#pragma unroll
  for (int s = 0; s < SPT; ++s) {
    float acc = fmaf(h[s][0], wo0, bo);
    acc = fmaf(h[s][1], wo1, acc);
    acc = fmaf(h[s][2], wo2, acc);
    acc = fmaf(h[s][3], wo3, acc);
    o[s] = acc;
  }
  float4* op4 = reinterpret_cast<float4*>(out) + tid * (SPT / 4);
#pragma unroll
  for (int q = 0; q < SPT / 4; ++q) {
    float4 v;
    v.x = o[4*q+0]; v.y = o[4*q+1]; v.z = o[4*q+2]; v.w = o[4*q+3];
    op4[q] = v;
  }
}

extern "C" void kernel_launch(void* const* d_in, const int* in_sizes, int n_in,
                              void* d_out, int out_size, void* d_ws, size_t ws_size,
                              hipStream_t stream) {
  const float* coords   = (const float*)d_in[0];
  const float* w_first  = (const float*)d_in[1];
  const float* b_first  = (const float*)d_in[2];
  const float* w_hidden = (const float*)d_in[3];
  const float* b_hidden = (const float*)d_in[4];
  const float* w_out    = (const float*)d_in[5];
  const float* b_out    = (const float*)d_in[6];
  const float* a_param  = (const float*)d_in[7];
  const float* b_param  = (const float*)d_in[8];
  const float* c_param  = (const float*)d_in[9];
  const float* d_param  = (const float*)d_in[10];
  float* ws   = (float*)d_ws;
  float* outp = (float*)d_out;

  prep_kernel<<<21, 256, 0, stream>>>(w_hidden, b_hidden, w_out, b_out,
                                      a_param, b_param, c_param, d_param, ws);

  const int threads = NSAMP / SPT;          // 524288
  siren_main<<<threads / 256, 256, 0, stream>>>(coords, w_first, b_first, ws, outp);
}